// Round 1
// baseline (200495.093 us; speedup 1.0000x reference)
//
#include <hip/hip_runtime.h>
#include <stdint.h>

// ---------------------------------------------------------------------------
// FastWaveNet autoregressive sampler, persistent-pipeline design.
//   - 30 layer groups x 8 CUs, weights register-resident.
//   - one release/acquire hop per layer; deterministic partial-sum gather.
//   - head: 2 CUs end1, 1 CU end2+softmax+inverse-CDF sample.
// ---------------------------------------------------------------------------

#define TT   1024
#define XTS  1025          // time slots for xhist (head writes t+1)
#define MAGIC 0x1337BEEFu

// byte offsets into d_ws
#define OFF_READY  0
#define OFF_CTR    1024                         // 32 counters, 64 B apart
#define OFF_GPART  4096                         // 240*256 f32 residual partials
#define OFF_SPART  (OFF_GPART + 240*256*4)      // 240*256 f32 skip partials
#define OFF_SBUF   (OFF_SPART + 240*256*4)      // 30*256 f32 running skip
#define OFF_HID    (OFF_SBUF + 30*256*4)        // 256 f32 head hidden
#define OFF_XH     (OFF_HID + 1024)             // 30*XTS*256 f32 x history
#define WS_NEED    ((size_t)OFF_XH + (size_t)30*XTS*256*4)

__device__ __forceinline__ unsigned ld_rlx(unsigned* p){
    return __hip_atomic_load(p, __ATOMIC_RELAXED, __HIP_MEMORY_SCOPE_AGENT);
}

__device__ __forceinline__ void spin_ge(unsigned* p, unsigned target, long long ddl){
    unsigned v = ld_rlx(p);
    int c = 0;
    while (v < target){
        if (((++c) & 2047) == 0 &&
            (long long)__builtin_amdgcn_s_memrealtime() > ddl) break;   // watchdog
        v = ld_rlx(p);
    }
    (void)__hip_atomic_load(p, __ATOMIC_ACQUIRE, __HIP_MEMORY_SCOPE_AGENT);
}

__device__ __forceinline__ void st_coh(float* p, float v){
    __hip_atomic_store(p, v, __ATOMIC_RELAXED, __HIP_MEMORY_SCOPE_AGENT);
}

__global__ void __launch_bounds__(256, 1)
wavenet_persist(const float* __restrict__ gy,   const float* __restrict__ gemb,
                const float* __restrict__ gcw,  const float* __restrict__ gwvp,
                const float* __restrict__ gwvx, const float* __restrict__ gwo,
                const float* __restrict__ gwob, const float* __restrict__ gwol,
                const float* __restrict__ gwobl,const float* __restrict__ ge1w,
                const float* __restrict__ ge1b, const float* __restrict__ ge2w,
                const float* __restrict__ ge2b, const float* __restrict__ gsmp,
                int* __restrict__ gout, char* __restrict__ ws)
{
    const int b = blockIdx.x, tid = threadIdx.x;
    // XCD-aware role map: block b lives on XCD b%8; layer j (8 blocks) sits on
    // XCD j>>2 so 3/4 of pipeline hops stay on one XCD.
    const int xcd = b & 7, kk = b >> 3;
    const int jj = 4*xcd + (kk >> 3);   // 0..29 layer, 30 head, 31 idle
    const int cc = kk & 7;

    if (jj > 30 || (jj == 30 && cc > 2)) return;   // idle blocks

    unsigned* ctrs  = (unsigned*)(ws + OFF_CTR);
    float*    gpart = (float*)(ws + OFF_GPART);
    float*    spart = (float*)(ws + OFF_SPART);
    float*    sbuf  = (float*)(ws + OFF_SBUF);
    float*    hid   = (float*)(ws + OFF_HID);
    float*    xh    = (float*)(ws + OFF_XH);
    unsigned* ready = (unsigned*)(ws + OFF_READY);
    auto CTR = [&](int i){ return ctrs + i*16; };   // 64 B spacing

    __shared__ float sX[512];
    __shared__ float sY[80];
    __shared__ float sH[64];
    __shared__ float sZ[32];
    __shared__ float sred[8];
    __shared__ int   sidx[4];

    const long long ddl = (long long)__builtin_amdgcn_s_memrealtime() + 400000000LL;
    const bool isH2 = (jj == 30 && cc == 2);

    // ---- in-kernel init (d_ws is poisoned 0xAA before every launch) ----
    if (isH2){
        if (tid < 32) CTR(tid)[0] = 0u;
        st_coh(&xh[tid], gemb[127*256 + tid]);      // xhist[0][0] = emb[127]
        __syncthreads();                            // drain before release
        if (tid == 0)
            __hip_atomic_store(ready, MAGIC, __ATOMIC_RELEASE, __HIP_MEMORY_SCOPE_AGENT);
    }

    // =======================================================================
    if (jj < 30){                                   // ---- layer block ----
        const int j   = jj;
        const int dil = 1 << (j % 10);
        const int q   = tid & 3;                    // 128-col chunk
        const int rl  = tid >> 2;                   // local row 0..63
        const int gr  = (rl < 32) ? (32*cc + rl) : (256 + 32*cc + (rl - 32));

        // --- register-resident weights ---
        // wv: 128 cols of [WV_past | WV_present] row gr, bank-staggered by 2q.
        const float* rw = (q < 2) ? (gwvp + ((size_t)j*512 + gr)*256 + 128*q)
                                  : (gwvx + ((size_t)j*512 + gr)*256 + 128*(q-2));
        float wv[128];
        #pragma unroll
        for (int i = 0; i < 32; i++){
            const int ci = (i + 2*q) & 31;
            wv[4*i+0] = rw[4*ci+0]; wv[4*i+1] = rw[4*ci+1];
            wv[4*i+2] = rw[4*ci+2]; wv[4*i+3] = rw[4*ci+3];
        }
        float cw[20];
        {
            const float* cp = gcw + ((size_t)(j*512 + gr))*80 + 20*q;
            #pragma unroll
            for (int i = 0; i < 20; i++) cw[i] = cp[i];
        }
        float wo2[64]; float bres = 0.f, bskip = 0.f;
        if (j < 29){
            const float* w0 = gwo + ((size_t)j*512 + tid)*256 + 32*cc;
            const float* w1 = gwo + ((size_t)j*512 + 256 + tid)*256 + 32*cc;
            #pragma unroll
            for (int i = 0; i < 32; i++){ wo2[i] = w0[i]; wo2[32+i] = w1[i]; }
            bres  = gwob[j*512 + tid];
            bskip = gwob[j*512 + 256 + tid];
        } else {
            const float* w0 = gwol + (size_t)tid*256 + 32*cc;
            #pragma unroll
            for (int i = 0; i < 32; i++){ wo2[i] = w0[i]; wo2[32+i] = 0.f; }
            bskip = gwobl[tid];
        }

        // wait for init
        if (tid == 0){
            unsigned v = ld_rlx(ready); int c2 = 0;
            while (v != MAGIC){
                if (((++c2) & 2047) == 0 &&
                    (long long)__builtin_amdgcn_s_memrealtime() > ddl) break;
                v = ld_rlx(ready);
            }
            (void)__hip_atomic_load(ready, __ATOMIC_ACQUIRE, __HIP_MEMORY_SCOPE_AGENT);
        }
        __syncthreads();

        unsigned* myc = CTR(j);
        unsigned* pvc = (j == 0) ? CTR(31) : CTR(j-1);
        float* xhj = xh + (size_t)j*XTS*256;
        const float* xhp = (j == 0) ? xh : (xh + (size_t)(j-1)*XTS*256);
        // d==1 taps are produced one chain-position too late for pre-spin read.
        const bool earlytap = (dil > 1);

        for (int t = 0; t < TT; t++){
            // ---- prefetch while waiting: y column, tap, cond partial ----
            if (tid < 80) sY[tid] = gy[tid*TT + t];
            if (earlytap) sX[tid] = (t >= dil) ? xhj[(t-dil)*256 + tid] : 0.f;
            __syncthreads();
            float acc = 0.f;
            #pragma unroll
            for (int i = 0; i < 20; i++) acc = fmaf(cw[i], sY[20*q + i], acc);

            const unsigned tgt = (j == 0) ? (unsigned)t : (unsigned)(8*(t+1));
            if (tid == 0) spin_ge(pvc, tgt, ddl);
            __syncthreads();

            // ---- gather x_j = x_{j-1} + sum of 8 residual partials ----
            if (!earlytap) sX[tid] = (t >= dil) ? xhj[(t-dil)*256 + tid] : 0.f;
            float xv;
            if (j == 0) xv = xh[t*256 + tid];
            else {
                xv = xhp[t*256 + tid];
                #pragma unroll
                for (int c2 = 0; c2 < 8; c2++)
                    xv += gpart[((j-1)*8 + c2)*256 + tid];
            }
            sX[256 + tid] = xv;
            if (cc == 0){
                st_coh(&xhj[t*256 + tid], xv);      // history for future taps
                if (j >= 1){                        // deterministic skip chain
                    float sv = (j >= 2) ? sbuf[(j-1)*256 + tid] : 0.f;
                    #pragma unroll
                    for (int c2 = 0; c2 < 8; c2++)
                        sv += spart[((j-1)*8 + c2)*256 + tid];
                    st_coh(&sbuf[j*256 + tid], sv);
                }
            }
            __syncthreads();

            // ---- h row: cond + WVpast@tap + WVpres@x (bank-staggered) ----
            const float4* xt4 = (const float4*)(sX + 128*q);
            #pragma unroll
            for (int i = 0; i < 32; i++){
                const int ci = (i + 2*q) & 31;
                float4 v = xt4[ci];
                acc = fmaf(wv[4*i+0], v.x, acc);
                acc = fmaf(wv[4*i+1], v.y, acc);
                acc = fmaf(wv[4*i+2], v.z, acc);
                acc = fmaf(wv[4*i+3], v.w, acc);
            }
            acc += __shfl_xor(acc, 1, 64);
            acc += __shfl_xor(acc, 2, 64);
            if (q == 0) sH[rl] = acc;
            __syncthreads();

            if (tid < 32){                          // gated activation
                float zw = sH[tid], zf = sH[tid + 32];
                sZ[tid] = tanhf(zw) * (1.f / (1.f + expf(-zf)));
            }
            __syncthreads();

            // ---- rank-32 column partial of W_o @ z ----
            float g = 0.f, s = 0.f;
            const float4* z4 = (const float4*)sZ;
            #pragma unroll
            for (int i = 0; i < 8; i++){
                float4 v = z4[i];
                g = fmaf(wo2[4*i+0], v.x, g); g = fmaf(wo2[4*i+1], v.y, g);
                g = fmaf(wo2[4*i+2], v.z, g); g = fmaf(wo2[4*i+3], v.w, g);
                s = fmaf(wo2[32+4*i+0], v.x, s); s = fmaf(wo2[32+4*i+1], v.y, s);
                s = fmaf(wo2[32+4*i+2], v.z, s); s = fmaf(wo2[32+4*i+3], v.w, s);
            }
            if (j < 29){
                if (cc == 0){ g += bres; s += bskip; }   // bias folded once
                st_coh(&gpart[(j*8 + cc)*256 + tid], g);
                st_coh(&spart[(j*8 + cc)*256 + tid], s);
            } else {
                if (cc == 0) g += bskip;                 // last layer: skip only
                st_coh(&spart[(29*8 + cc)*256 + tid], g);
            }
            __syncthreads();                              // drain all lanes' stores
            if (tid == 0)
                __hip_atomic_fetch_add(myc, 1u, __ATOMIC_RELEASE, __HIP_MEMORY_SCOPE_AGENT);
        }
        return;
    }

    // =======================================================================
    if (jj == 30 && cc < 2){                        // ---- H1: end1 ----
        const int half = cc;
        const int r  = 128*half + (tid >> 1);
        const int hc = tid & 1;
        float e1[128];
        {
            const float* wp = ge1w + (size_t)r*256 + 128*hc;
            #pragma unroll
            for (int i = 0; i < 128; i++) e1[i] = wp[i];
        }
        const float b1 = ge1b[r];

        if (tid == 0){
            unsigned v = ld_rlx(ready); int c2 = 0;
            while (v != MAGIC){
                if (((++c2) & 2047) == 0 &&
                    (long long)__builtin_amdgcn_s_memrealtime() > ddl) break;
                v = ld_rlx(ready);
            }
            (void)__hip_atomic_load(ready, __ATOMIC_ACQUIRE, __HIP_MEMORY_SCOPE_AGENT);
        }
        __syncthreads();

        for (int t = 0; t < TT; t++){
            if (tid == 0) spin_ge(CTR(29), 8u*(t+1), ddl);
            __syncthreads();
            float sk = sbuf[29*256 + tid];
            #pragma unroll
            for (int c2 = 0; c2 < 8; c2++)
                sk += spart[(29*8 + c2)*256 + tid];
            sX[tid] = fmaxf(sk, 0.f);               // relu(skip)
            __syncthreads();
            float a = 0.f;
            const float4* p4 = (const float4*)(sX + 128*hc);
            #pragma unroll
            for (int i = 0; i < 32; i++){
                float4 v = p4[i];
                a = fmaf(e1[4*i+0], v.x, a); a = fmaf(e1[4*i+1], v.y, a);
                a = fmaf(e1[4*i+2], v.z, a); a = fmaf(e1[4*i+3], v.w, a);
            }
            a += __shfl_xor(a, 1, 64);
            if (hc == 0) st_coh(&hid[r], fmaxf(a + b1, 0.f));
            __syncthreads();
            if (tid == 0)
                __hip_atomic_fetch_add(CTR(30), 1u, __ATOMIC_RELEASE, __HIP_MEMORY_SCOPE_AGENT);
        }
        return;
    }

    // =======================================================================
    {                                               // ---- H2: end2 + sample ----
        float e2[256];
        {
            const float* wp = ge2w + (size_t)tid*256;
            #pragma unroll
            for (int i = 0; i < 256; i++) e2[i] = wp[i];
        }
        const float b2 = ge2b[tid];
        const int w = tid >> 6, lane = tid & 63;

        for (int t = 0; t < TT; t++){
            if (tid == 0) spin_ge(CTR(30), 2u*(t+1), ddl);
            __syncthreads();
            sX[tid] = hid[tid];
            __syncthreads();
            float a = b2;
            const float4* p4 = (const float4*)sX;
            #pragma unroll
            for (int i = 0; i < 64; i++){
                float4 v = p4[i];
                a = fmaf(e2[4*i+0], v.x, a); a = fmaf(e2[4*i+1], v.y, a);
                a = fmaf(e2[4*i+2], v.z, a); a = fmaf(e2[4*i+3], v.w, a);
            }
            // softmax (ref order: p = e/(sum e), then cumsum, first cum > u)
            float m = a;
            #pragma unroll
            for (int off = 32; off > 0; off >>= 1) m = fmaxf(m, __shfl_xor(m, off, 64));
            if (lane == 0) sred[w] = m;
            __syncthreads();
            m = fmaxf(fmaxf(sred[0], sred[1]), fmaxf(sred[2], sred[3]));
            float pe = expf(a - m);
            float ssum = pe;
            #pragma unroll
            for (int off = 32; off > 0; off >>= 1) ssum += __shfl_xor(ssum, off, 64);
            if (lane == 0) sred[4 + w] = ssum;
            __syncthreads();
            const float S = sred[4] + sred[5] + sred[6] + sred[7];
            float cum = pe / S;
            #pragma unroll
            for (int off = 1; off < 64; off <<= 1){
                float vv = __shfl_up(cum, off, 64);
                if (lane >= off) cum += vv;
            }
            if (lane == 63) sred[w] = cum;          // wave totals (indices 0..3 free)
            __syncthreads();
            float base = 0.f;
            if (w > 0) base += sred[0];
            if (w > 1) base += sred[1];
            if (w > 2) base += sred[2];
            cum += base;
            const float u = gsmp[t];
            unsigned long long bal = __ballot(cum > u);
            int cand = bal ? (w*64 + __ffsll((long long)bal) - 1) : (1 << 30);
            if (lane == 0) sidx[w] = cand;
            __syncthreads();
            int idx = min(min(sidx[0], sidx[1]), min(sidx[2], sidx[3]));
            if (idx > 255) idx = 0;                 // argmax of all-false = 0
            if (tid == 0) gout[t] = idx;
            st_coh(&xh[(t+1)*256 + tid], gemb[idx*256 + tid]);  // next x_0
            __syncthreads();
            if (tid == 0)
                __hip_atomic_fetch_add(CTR(31), 1u, __ATOMIC_RELEASE, __HIP_MEMORY_SCOPE_AGENT);
        }
        return;
    }
}

__global__ void ws_too_small_kernel(int* out, int n){
    int i = blockIdx.x*256 + threadIdx.x;
    if (i < n) out[i] = 0;
}

extern "C" void kernel_launch(void* const* d_in, const int* in_sizes, int n_in,
                              void* d_out, int out_size, void* d_ws, size_t ws_size,
                              hipStream_t stream){
    (void)in_sizes; (void)n_in;
    if (ws_size < WS_NEED){
        hipLaunchKernelGGL(ws_too_small_kernel, dim3(4), dim3(256), 0, stream,
                           (int*)d_out, out_size);
        return;
    }
    hipLaunchKernelGGL(wavenet_persist, dim3(256), dim3(256), 0, stream,
                       (const float*)d_in[0],  (const float*)d_in[1],
                       (const float*)d_in[2],  (const float*)d_in[3],
                       (const float*)d_in[4],  (const float*)d_in[5],
                       (const float*)d_in[6],  (const float*)d_in[7],
                       (const float*)d_in[8],  (const float*)d_in[9],
                       (const float*)d_in[10], (const float*)d_in[11],
                       (const float*)d_in[12], (const float*)d_in[13],
                       (int*)d_out, (char*)d_ws);
}

// Round 2
// 108535.779 us; speedup vs baseline: 1.8473x; 1.8473x over previous
//
#include <hip/hip_runtime.h>
#include <stdint.h>

// ---------------------------------------------------------------------------
// FastWaveNet autoregressive sampler v2 — persistent pipeline with
// self-validating stamped 64-bit records (no counters, no fences on the
// critical path), raw s_barrier (no vmcnt drain), register-pinned weights.
// Compute op order is bit-identical to the round-1 kernel.
// ---------------------------------------------------------------------------

typedef unsigned long long u64;

#define TT 1024

// byte offsets into d_ws (all 8-B aligned)
#define OFF_PG   0                              // 30*8*256 stamped g-partials
#define OFF_PS   (OFF_PG + 30*8*256*8)          // 30*8*256 stamped s-partials
#define OFF_XV   (OFF_PS + 30*8*256*8)          // 30*256 stamped x values
#define OFF_SB   (OFF_XV + 30*256*8)            // 30*256 stamped running skip
#define OFF_HID  (OFF_SB + 30*256*8)            // 256 stamped head hidden
#define OFF_IDX  (OFF_HID + 256*8)              // 1 stamped sampled index
#define OFF_XH   (OFF_IDX + 64)                 // 30*1024*256 f32 x history
#define WS_NEED  ((size_t)OFF_XH + (size_t)30*1024*256*4)

__device__ __forceinline__ u64 ldp(const u64* p){
    return __hip_atomic_load((u64*)p, __ATOMIC_RELAXED, __HIP_MEMORY_SCOPE_AGENT);
}
__device__ __forceinline__ void stp(u64* p, float v, unsigned stamp){
    union { float f; unsigned u; } c; c.f = v;
    u64 w = ((u64)stamp << 32) | (u64)c.u;
    __hip_atomic_store(p, w, __ATOMIC_RELAXED, __HIP_MEMORY_SCOPE_AGENT);
}
__device__ __forceinline__ void stpu(u64* p, unsigned v, unsigned stamp){
    u64 w = ((u64)stamp << 32) | (u64)v;
    __hip_atomic_store(p, w, __ATOMIC_RELAXED, __HIP_MEMORY_SCOPE_AGENT);
}
__device__ __forceinline__ float pf(u64 w){
    union { unsigned u; float f; } c; c.u = (unsigned)(w & 0xffffffffu); return c.f;
}
__device__ __forceinline__ unsigned pstamp(u64 w){ return (unsigned)(w >> 32); }
__device__ __forceinline__ float ldf(const float* p){
    return __hip_atomic_load((float*)p, __ATOMIC_RELAXED, __HIP_MEMORY_SCOPE_AGENT);
}
__device__ __forceinline__ void stf(float* p, float v){
    __hip_atomic_store(p, v, __ATOMIC_RELAXED, __HIP_MEMORY_SCOPE_AGENT);
}
__device__ __forceinline__ long long rt(){
    return (long long)__builtin_amdgcn_s_memrealtime();
}
// raw barrier: LDS visibility only — does NOT drain vmcnt (in-flight global
// stores keep flying; poll loops' own s_waitcnt retires them each step).
__device__ __forceinline__ void bar_lds(){
    asm volatile("s_waitcnt lgkmcnt(0)\n\ts_barrier" ::: "memory");
}

__global__ void __launch_bounds__(256, 1)
wavenet_v2(const float* __restrict__ gy,   const float* __restrict__ gemb,
           const float* __restrict__ gcw,  const float* __restrict__ gwvp,
           const float* __restrict__ gwvx, const float* __restrict__ gwo,
           const float* __restrict__ gwob, const float* __restrict__ gwol,
           const float* __restrict__ gwobl,const float* __restrict__ ge1w,
           const float* __restrict__ ge1b, const float* __restrict__ ge2w,
           const float* __restrict__ ge2b, const float* __restrict__ gsmp,
           float one, int* __restrict__ gout, char* __restrict__ ws)
{
    const int b = blockIdx.x, tid = threadIdx.x;
    // XCD-aware role map (performance heuristic only): layer j on XCD j>>2.
    const int xcd = b & 7, kk = b >> 3;
    const int jj = 4*xcd + (kk >> 3);   // 0..29 layer, 30 head, 31 idle
    const int cc = kk & 7;

    if (jj > 30 || (jj == 30 && cc > 2)) return;   // idle blocks

    u64* PG   = (u64*)(ws + OFF_PG);
    u64* PS   = (u64*)(ws + OFF_PS);
    u64* XV   = (u64*)(ws + OFF_XV);
    u64* SB   = (u64*)(ws + OFF_SB);
    u64* HIDP = (u64*)(ws + OFF_HID);
    u64* IDXP = (u64*)(ws + OFF_IDX);
    float* xh = (float*)(ws + OFF_XH);

    __shared__ float sTap[256];     // tap column (layers) / sX (head)
    __shared__ float sXin[256];     // present x column
    __shared__ float sY[80];
    __shared__ float sZ[32];
    __shared__ float sred[8];
    __shared__ int   sidx[4];

    const long long ddl = rt() + 400000000LL;      // watchdog: wrong, not hung

    // =======================================================================
    if (jj < 30){                                   // ---- layer block ----
        const int j   = jj;
        const int dil = 1 << (j % 10);
        const int q   = tid & 3;                    // 128-col chunk
        const int s   = (tid >> 2) & 15;            // slot in wave
        const int w   = tid >> 6;                   // wave
        // row remap: zw/zf partners 32 lanes apart (shfl_xor 32 gate).
        const int gr  = (s < 8) ? (32*cc + 8*w + s)
                                : (256 + 32*cc + 8*w + (s - 8));

        // --- register-resident weights (×one blocks rematerialization) ---
        const float* rw = (q < 2) ? (gwvp + ((size_t)j*512 + gr)*256 + 128*q)
                                  : (gwvx + ((size_t)j*512 + gr)*256 + 128*(q-2));
        float wv[128];
        #pragma unroll
        for (int i = 0; i < 32; i++){
            const int ci = (i + 2*q) & 31;
            wv[4*i+0] = rw[4*ci+0]*one; wv[4*i+1] = rw[4*ci+1]*one;
            wv[4*i+2] = rw[4*ci+2]*one; wv[4*i+3] = rw[4*ci+3]*one;
        }
        float cw[20];
        {
            const float* cp = gcw + ((size_t)(j*512 + gr))*80 + 20*q;
            #pragma unroll
            for (int i = 0; i < 20; i++) cw[i] = cp[i]*one;
        }
        float wo2[64]; float bres = 0.f, bskip = 0.f;
        if (j < 29){
            const float* w0 = gwo + ((size_t)j*512 + tid)*256 + 32*cc;
            const float* w1 = gwo + ((size_t)j*512 + 256 + tid)*256 + 32*cc;
            #pragma unroll
            for (int i = 0; i < 32; i++){ wo2[i] = w0[i]*one; wo2[32+i] = w1[i]*one; }
            bres  = gwob[j*512 + tid];
            bskip = gwob[j*512 + 256 + tid];
        } else {
            const float* w0 = gwol + (size_t)tid*256 + 32*cc;
            #pragma unroll
            for (int i = 0; i < 32; i++){ wo2[i] = w0[i]*one; wo2[32+i] = 0.f; }
            bskip = gwobl[tid];
        }

        u64* pgj = PG + (size_t)j*8*256;
        u64* psj = PS + (size_t)j*8*256;
        const u64* pgp = PG + (size_t)(j > 0 ? j-1 : 0)*8*256 + tid;
        const u64* psp = PS + (size_t)(j > 0 ? j-1 : 0)*8*256 + tid;
        const u64* xvp = XV + (size_t)(j > 0 ? j-1 : 0)*256 + tid;
        const u64* sbp = SB + (size_t)(j >= 2 ? j-1 : 0)*256 + tid;
        float* xhj = xh + (size_t)j*1024*256;
        float xv_prev = 0.f;

        for (int t = 0; t < TT; t++){
            const unsigned stamp = (unsigned)(t + 1);

            // ---- slack phase: stage cond column + dilated tap ----
            if (tid < 80) sY[tid] = gy[tid*TT + t];
            float tapv;
            if (dil == 1) tapv = xv_prev;
            else          tapv = (t >= dil) ? ldf(xhj + (size_t)(t-dil)*256 + tid) : 0.f;
            sTap[tid] = tapv;
            bar_lds();

            float acc = 0.f;
            #pragma unroll
            for (int i = 0; i < 20; i++) acc = fmaf(cw[i], sY[20*q + i], acc);
            if (q < 2){                              // WV_past half: pre-poll
                const float4* x4 = (const float4*)(sTap + 128*q);
                #pragma unroll
                for (int i = 0; i < 32; i++){
                    const int ci = (i + 2*q) & 31;
                    float4 v = x4[ci];
                    acc = fmaf(wv[4*i+0], v.x, acc); acc = fmaf(wv[4*i+1], v.y, acc);
                    acc = fmaf(wv[4*i+2], v.z, acc); acc = fmaf(wv[4*i+3], v.w, acc);
                }
            }

            // ---- poll stamped records; payload arrives with the detect ----
            float xv;
            if (j == 0){
                if (t == 0){
                    xv = gemb[127*256 + tid];
                } else {
                    u64 wIdx; int c = 0;
                    do {
                        wIdx = ldp(IDXP);
                        if (((++c) & 255) == 0 && rt() > ddl) break;
                    } while (pstamp(wIdx) != (unsigned)t);
                    const int idx = (int)(wIdx & 0xffffffffu) & 255;
                    xv = gemb[idx*256 + tid];        // emb is read-only: cached
                }
            } else {
                u64 gwv[8]; u64 xvw = 0; u64 swv[8]; u64 sbw = 0;
                bool fresh; int c = 0;
                do {
                    #pragma unroll
                    for (int c2 = 0; c2 < 8; c2++) gwv[c2] = ldp(pgp + c2*256);
                    xvw = ldp(xvp);
                    bool ok = (pstamp(xvw) == stamp);
                    #pragma unroll
                    for (int c2 = 0; c2 < 8; c2++) ok &= (pstamp(gwv[c2]) == stamp);
                    if (cc == 0){
                        #pragma unroll
                        for (int c2 = 0; c2 < 8; c2++){
                            swv[c2] = ldp(psp + c2*256);
                            ok &= (pstamp(swv[c2]) == stamp);
                        }
                        if (j >= 2){ sbw = ldp(sbp); ok &= (pstamp(sbw) == stamp); }
                    }
                    fresh = ok;
                    if (((++c) & 255) == 0 && rt() > ddl) break;
                } while (!fresh);
                xv = pf(xvw);                        // same gather order as r1
                #pragma unroll
                for (int c2 = 0; c2 < 8; c2++) xv += pf(gwv[c2]);
                if (cc == 0){                        // deterministic skip chain
                    float sv = (j >= 2) ? pf(sbw) : 0.f;
                    #pragma unroll
                    for (int c2 = 0; c2 < 8; c2++) sv += pf(swv[c2]);
                    stp(SB + (size_t)j*256 + tid, sv, stamp);
                }
            }
            xv_prev = xv;
            sXin[tid] = xv;
            if (cc == 0){
                stp(XV + (size_t)j*256 + tid, xv, stamp);   // x_j for layer j+1
                if (dil > 1) stf(xhj + (size_t)t*256 + tid, xv); // own future tap
            }
            bar_lds();

            if (q >= 2){                             // WV_present half: post-poll
                const float4* x4 = (const float4*)(sXin + 128*(q-2));
                #pragma unroll
                for (int i = 0; i < 32; i++){
                    const int ci = (i + 2*q) & 31;
                    float4 v = x4[ci];
                    acc = fmaf(wv[4*i+0], v.x, acc); acc = fmaf(wv[4*i+1], v.y, acc);
                    acc = fmaf(wv[4*i+2], v.z, acc); acc = fmaf(wv[4*i+3], v.w, acc);
                }
            }
            acc += __shfl_xor(acc, 1, 64);
            acc += __shfl_xor(acc, 2, 64);
            const float hpart = __shfl_xor(acc, 32, 64);   // zf partner
            if (q == 0 && s < 8)
                sZ[8*w + s] = tanhf(acc) * (1.f/(1.f + expf(-hpart)));
            bar_lds();

            // ---- rank-32 column partial of W_o @ z ----
            float g = 0.f, sk = 0.f;
            const float4* z4 = (const float4*)sZ;
            #pragma unroll
            for (int i = 0; i < 8; i++){
                float4 v = z4[i];
                g  = fmaf(wo2[4*i+0], v.x, g);  g  = fmaf(wo2[4*i+1], v.y, g);
                g  = fmaf(wo2[4*i+2], v.z, g);  g  = fmaf(wo2[4*i+3], v.w, g);
                sk = fmaf(wo2[32+4*i+0], v.x, sk); sk = fmaf(wo2[32+4*i+1], v.y, sk);
                sk = fmaf(wo2[32+4*i+2], v.z, sk); sk = fmaf(wo2[32+4*i+3], v.w, sk);
            }
            if (j < 29){
                if (cc == 0){ g += bres; sk += bskip; }     // bias folded once
                stp(pgj + cc*256 + tid, g,  stamp);
                stp(psj + cc*256 + tid, sk, stamp);
            } else {
                if (cc == 0) g += bskip;                    // last layer: skip only
                stp(psj + cc*256 + tid, g, stamp);
            }
            // no drain, no flag: stores self-describe via their stamps
        }
        return;
    }

    // =======================================================================
    if (jj == 30 && cc < 2){                        // ---- H1: end1 ----
        const int half = cc;
        const int r  = 128*half + (tid >> 1);
        const int hc = tid & 1;
        float e1[128];
        {
            const float* wp = ge1w + (size_t)r*256 + 128*hc;
            #pragma unroll
            for (int i = 0; i < 128; i++) e1[i] = wp[i]*one;
        }
        const float b1 = ge1b[r];
        const u64* psp = PS + (size_t)29*8*256 + tid;
        const u64* sbp = SB + (size_t)29*256 + tid;

        for (int t = 0; t < TT; t++){
            const unsigned stamp = (unsigned)(t + 1);
            u64 swv[8]; u64 sbw = 0; bool fresh; int c = 0;
            do {
                #pragma unroll
                for (int c2 = 0; c2 < 8; c2++) swv[c2] = ldp(psp + c2*256);
                sbw = ldp(sbp);
                bool ok = (pstamp(sbw) == stamp);
                #pragma unroll
                for (int c2 = 0; c2 < 8; c2++) ok &= (pstamp(swv[c2]) == stamp);
                fresh = ok;
                if (((++c) & 255) == 0 && rt() > ddl) break;
            } while (!fresh);
            float sk = pf(sbw);
            #pragma unroll
            for (int c2 = 0; c2 < 8; c2++) sk += pf(swv[c2]);
            sTap[tid] = fmaxf(sk, 0.f);             // relu(skip)
            bar_lds();
            float a = 0.f;
            const float4* p4 = (const float4*)(sTap + 128*hc);
            #pragma unroll
            for (int i = 0; i < 32; i++){
                float4 v = p4[i];
                a = fmaf(e1[4*i+0], v.x, a); a = fmaf(e1[4*i+1], v.y, a);
                a = fmaf(e1[4*i+2], v.z, a); a = fmaf(e1[4*i+3], v.w, a);
            }
            a += __shfl_xor(a, 1, 64);
            if (hc == 0) stp(HIDP + r, fmaxf(a + b1, 0.f), stamp);
            bar_lds();                               // sTap reuse guard
        }
        return;
    }

    // =======================================================================
    {                                               // ---- H2: end2 + sample ----
        float e2[256];
        {
            const float* wp = ge2w + (size_t)tid*256;
            #pragma unroll
            for (int i = 0; i < 256; i++) e2[i] = wp[i]*one;
        }
        const float b2 = ge2b[tid];
        const int w = tid >> 6, lane = tid & 63;

        for (int t = 0; t < TT; t++){
            const unsigned stamp = (unsigned)(t + 1);
            u64 hw; int c = 0;
            do {
                hw = ldp(HIDP + tid);
                if (((++c) & 255) == 0 && rt() > ddl) break;
            } while (pstamp(hw) != stamp);
            sTap[tid] = pf(hw);
            bar_lds();
            float a = b2;
            const float4* p4 = (const float4*)sTap;
            #pragma unroll
            for (int i = 0; i < 64; i++){
                float4 v = p4[i];
                a = fmaf(e2[4*i+0], v.x, a); a = fmaf(e2[4*i+1], v.y, a);
                a = fmaf(e2[4*i+2], v.z, a); a = fmaf(e2[4*i+3], v.w, a);
            }
            // softmax + cumsum + first cum > u (identical op order to round 1)
            float m = a;
            #pragma unroll
            for (int off = 32; off > 0; off >>= 1) m = fmaxf(m, __shfl_xor(m, off, 64));
            if (lane == 0) sred[w] = m;
            bar_lds();
            m = fmaxf(fmaxf(sred[0], sred[1]), fmaxf(sred[2], sred[3]));
            float pe = expf(a - m);
            float ssum = pe;
            #pragma unroll
            for (int off = 32; off > 0; off >>= 1) ssum += __shfl_xor(ssum, off, 64);
            if (lane == 0) sred[4 + w] = ssum;
            bar_lds();
            const float S = sred[4] + sred[5] + sred[6] + sred[7];
            float cum = pe / S;
            #pragma unroll
            for (int off = 1; off < 64; off <<= 1){
                float vv = __shfl_up(cum, off, 64);
                if (lane >= off) cum += vv;
            }
            if (lane == 63) sred[w] = cum;
            bar_lds();
            float base = 0.f;
            if (w > 0) base += sred[0];
            if (w > 1) base += sred[1];
            if (w > 2) base += sred[2];
            cum += base;
            const float u = gsmp[t];
            unsigned long long bal = __ballot(cum > u);
            int cand = bal ? (w*64 + __ffsll((long long)bal) - 1) : (1 << 30);
            if (lane == 0) sidx[w] = cand;
            bar_lds();
            int idx = min(min(sidx[0], sidx[1]), min(sidx[2], sidx[3]));
            if (idx > 255) idx = 0;
            if (tid == 0){
                gout[t] = idx;
                stpu(IDXP, (unsigned)idx, stamp);    // feedback to layer 0
            }
            bar_lds();                               // sred/sidx reuse guard
        }
        return;
    }
}

__global__ void ws_too_small_kernel(int* out, int n){
    int i = blockIdx.x*256 + threadIdx.x;
    if (i < n) out[i] = 0;
}

extern "C" void kernel_launch(void* const* d_in, const int* in_sizes, int n_in,
                              void* d_out, int out_size, void* d_ws, size_t ws_size,
                              hipStream_t stream){
    (void)in_sizes; (void)n_in;
    if (ws_size < WS_NEED){
        hipLaunchKernelGGL(ws_too_small_kernel, dim3(4), dim3(256), 0, stream,
                           (int*)d_out, out_size);
        return;
    }
    hipLaunchKernelGGL(wavenet_v2, dim3(256), dim3(256), 0, stream,
                       (const float*)d_in[0],  (const float*)d_in[1],
                       (const float*)d_in[2],  (const float*)d_in[3],
                       (const float*)d_in[4],  (const float*)d_in[5],
                       (const float*)d_in[6],  (const float*)d_in[7],
                       (const float*)d_in[8],  (const float*)d_in[9],
                       (const float*)d_in[10], (const float*)d_in[11],
                       (const float*)d_in[12], (const float*)d_in[13],
                       1.0f, (int*)d_out, (char*)d_ws);
}